// Round 9
// baseline (156.751 us; speedup 1.0000x reference)
//
#include <hip/hip_runtime.h>

// LSHAttention: reference returns ONLY sticker = argsort(buckets) [B,S] int32.
// B=4, S=4096, D=1024, NR=32, 64 buckets.
//
// k1 (fused): grid 512 = (b:4, c32:128), 256 thr = 4 waves, full K in block.
//   Thread = (tok_t:2, r_t:4, kl:8); wave w; k-quad kappa = w*8+kl per tile.
//   Tile = 128 k, double-buffered. ALL LDS accesses conflict-free by design:
//     Q LDS [tok][kq f4] natural; stage slot = t+256i (linear); hot read
//       group = kappa&7 = kl -> 8 groups x 2 addrs (broadcast) = free.
//     R LDS b64-swizzled: slot64 = K*16 + (r2 ^ ((K>>2)&7)); stage linear with
//       pre-swizzled GLOBAL source (perm within 128B, coalesced) + per-thread
//       constant half-swap; hot read b64: group16 = (r_t*4+p)^kl -> 2/group.
//   acc = 16 tok x 8 r = 128 f32; 512 FMA per 16 b128(Q) + 16 b64(R) per tile.
//   Async stage: issue tile tau+1 global loads BEFORE compute(tau), LDS-write
//   after compute, ONE barrier per tile. Epilogue: shfl_xor(1) pair-reduce,
//   16-slice LDS dump, 256-thr sum, in-block argmax + bucket + 32-token hist.
// k2: offset scan (128 chunks); k3: stable scatter (verified round 7, verbatim).

#define B_DIM 4
#define S_LEN 4096
#define D_DIM 1024
#define NRR 32
#define NBK 64
#define TMK 32                  // tokens per block = hist chunk
#define NC32 (S_LEN / TMK)      // 128 chunks
#define TILE_K 128
#define NT (D_DIM / TILE_K)     // 8 tiles

__global__ __launch_bounds__(256) __attribute__((amdgpu_waves_per_eu(2, 2)))
void k1_buckets(const float* __restrict__ Q, const float* __restrict__ R,
                int* __restrict__ buckets, int* __restrict__ hist)
{
    __shared__ float4 smem4[4096];   // Q0 Q1 R0 R1 (16KB each); reused as slices
    __shared__ float xs[TMK * 33];
    __shared__ int cnt[NBK];

    const int t = threadIdx.x;
    const int b = blockIdx.x >> 7;
    const int c32 = blockIdx.x & 127;

    const int lane = t & 63;
    const int w = t >> 6;
    const int tok_t = lane >> 5;        // 16 tokens each
    const int r_t = (lane >> 3) & 3;    // 8 r each
    const int kl = lane & 7;
    const int kappa = w * 8 + kl;       // k-quad within tile

    const float4* Qg4 = (const float4*)(Q + ((size_t)b * S_LEN + c32 * TMK) * D_DIM);
    const float4* Rg4 = (const float4*)(R + (size_t)b * D_DIM * NRR);

    // ---- staging source pointers (per-thread constant; advance by tile) ----
    const float4* qsrc[4];
    const float4* rsrc[4];
#pragma unroll
    for (int i = 0; i < 4; ++i) {
        const int s = t + 256 * i;
        qsrc[i] = Qg4 + (size_t)(s >> 5) * 256 + (s & 31);
        const int K = s >> 3;
        rsrc[i] = Rg4 + (size_t)K * 8 + ((s & 7) ^ ((K >> 3) & 3));
    }
    const int rswap = (t >> 5) & 1;     // half-swap flag ((K>>2)&1), i-invariant

    float2 acc[16][4];
#pragma unroll
    for (int j = 0; j < 16; ++j)
#pragma unroll
        for (int p = 0; p < 4; ++p) acc[j][p] = make_float2(0.f, 0.f);

    // hot-loop constant LDS indices
    const int qoff = tok_t * 512 + kappa;          // f4 slot, + J*32
    int rboff[4];                                  // b64 slot, + kk*16
#pragma unroll
    for (int p = 0; p < 4; ++p) rboff[p] = kappa * 64 + ((r_t * 4 + p) ^ kl);

#define LOADS(TILE)                                                           \
    float4 qld[4], rld[4];                                                    \
    _Pragma("unroll")                                                         \
    for (int i = 0; i < 4; ++i) {                                             \
        qld[i] = qsrc[i][(TILE) * 32];                                        \
        float4 v = rsrc[i][(TILE) * 1024];                                    \
        rld[i] = rswap ? make_float4(v.z, v.w, v.x, v.y) : v;                 \
    }

#define WRITES(DST)                                                           \
    {                                                                         \
        float4* qb = smem4 + (DST) * 1024;                                    \
        float4* rb = smem4 + 2048 + (DST) * 1024;                             \
        _Pragma("unroll")                                                     \
        for (int i = 0; i < 4; ++i) {                                         \
            qb[t + 256 * i] = qld[i];                                         \
            rb[t + 256 * i] = rld[i];                                         \
        }                                                                     \
    }

    {   // prologue: tile 0 into buffer 0
        LOADS(0)
        WRITES(0)
    }
    __syncthreads();

    for (int tau = 0; tau < NT; ++tau) {
        const int cur = tau & 1;
        if (tau + 1 < NT) {
            LOADS(tau + 1)
            // ---- compute tile tau while loads are in flight ----
            {
                const float4* qb = smem4 + cur * 1024;
                const float2* rb = (const float2*)(smem4 + 2048 + cur * 1024);
                float2 rv[4][4];
#pragma unroll
                for (int kk = 0; kk < 4; ++kk)
#pragma unroll
                    for (int p = 0; p < 4; ++p)
                        rv[kk][p] = rb[rboff[p] + kk * 16];
#pragma unroll
                for (int tq = 0; tq < 4; ++tq) {
                    float4 qv[4];
#pragma unroll
                    for (int jj = 0; jj < 4; ++jj)
                        qv[jj] = qb[qoff + (tq * 4 + jj) * 32];
#pragma unroll
                    for (int jj = 0; jj < 4; ++jj)
#pragma unroll
                        for (int kk = 0; kk < 4; ++kk) {
                            const float s = kk == 0 ? qv[jj].x : kk == 1 ? qv[jj].y
                                          : kk == 2 ? qv[jj].z : qv[jj].w;
#pragma unroll
                            for (int p = 0; p < 4; ++p) {
                                acc[tq * 4 + jj][p].x = fmaf(s, rv[kk][p].x, acc[tq * 4 + jj][p].x);
                                acc[tq * 4 + jj][p].y = fmaf(s, rv[kk][p].y, acc[tq * 4 + jj][p].y);
                            }
                        }
                }
            }
            WRITES(cur ^ 1)
        } else {
            // last tile: compute only
            const float4* qb = smem4 + cur * 1024;
            const float2* rb = (const float2*)(smem4 + 2048 + cur * 1024);
            float2 rv[4][4];
#pragma unroll
            for (int kk = 0; kk < 4; ++kk)
#pragma unroll
                for (int p = 0; p < 4; ++p)
                    rv[kk][p] = rb[rboff[p] + kk * 16];
#pragma unroll
            for (int tq = 0; tq < 4; ++tq) {
                float4 qv[4];
#pragma unroll
                for (int jj = 0; jj < 4; ++jj)
                    qv[jj] = qb[qoff + (tq * 4 + jj) * 32];
#pragma unroll
                for (int jj = 0; jj < 4; ++jj)
#pragma unroll
                    for (int kk = 0; kk < 4; ++kk) {
                        const float s = kk == 0 ? qv[jj].x : kk == 1 ? qv[jj].y
                                      : kk == 2 ? qv[jj].z : qv[jj].w;
#pragma unroll
                        for (int p = 0; p < 4; ++p) {
                            acc[tq * 4 + jj][p].x = fmaf(s, rv[kk][p].x, acc[tq * 4 + jj][p].x);
                            acc[tq * 4 + jj][p].y = fmaf(s, rv[kk][p].y, acc[tq * 4 + jj][p].y);
                        }
                    }
            }
        }
        __syncthreads();
    }
#undef LOADS
#undef WRITES

    // ---- pair-reduce over kl bit0 (lanes l, l^1 share (tok_t, r_t)) ----
#pragma unroll
    for (int j = 0; j < 16; ++j)
#pragma unroll
        for (int p = 0; p < 4; ++p) {
            acc[j][p].x += __shfl_xor(acc[j][p].x, 1, 64);
            acc[j][p].y += __shfl_xor(acc[j][p].y, 1, 64);
        }

    // ---- dump 16 slices [32 tok][8 rq f4] over the whole 64KB smem ----
    if ((kl & 1) == 0) {
        const int slice = w * 4 + (kl >> 1);
#pragma unroll
        for (int j = 0; j < 16; ++j) {
            const int tok = tok_t * 16 + j;
            smem4[slice * 256 + tok * 8 + r_t * 2 + 0] =
                make_float4(acc[j][0].x, acc[j][0].y, acc[j][1].x, acc[j][1].y);
            smem4[slice * 256 + tok * 8 + r_t * 2 + 1] =
                make_float4(acc[j][2].x, acc[j][2].y, acc[j][3].x, acc[j][3].y);
        }
    }
    if (t < NBK) cnt[t] = 0;
    __syncthreads();

    // ---- final sum over 16 slices (conflict-free: consecutive slots) ----
    {
        float4 s = smem4[t];
#pragma unroll
        for (int sl = 1; sl < 16; ++sl) {
            const float4 v = smem4[sl * 256 + t];
            s.x += v.x; s.y += v.y; s.z += v.z; s.w += v.w;
        }
        const int tok = t >> 3, rq = t & 7;
        xs[tok * 33 + rq * 4 + 0] = s.x;
        xs[tok * 33 + rq * 4 + 1] = s.y;
        xs[tok * 33 + rq * 4 + 2] = s.z;
        xs[tok * 33 + rq * 4 + 3] = s.w;
    }
    __syncthreads();

    if (t < TMK) {
        // argmax(concat[xR,-xR]) with first-occurrence tie-break
        float m1 = xs[t * 33 + 0]; int i1 = 0;
        float m2 = m1;             int i2 = 0;
#pragma unroll
        for (int r = 1; r < NRR; ++r) {
            const float v = xs[t * 33 + r];
            if (v > m1) { m1 = v; i1 = r; }
            if (v < m2) { m2 = v; i2 = r; }
        }
        const int bk = (m1 >= -m2) ? i1 : (NRR + i2);
        buckets[(size_t)b * S_LEN + c32 * TMK + t] = bk;
        atomicAdd(&cnt[bk], 1);
    }
    __syncthreads();
    if (t < NBK) hist[((size_t)b * NC32 + c32) * NBK + t] = cnt[t];
}

// One block, 256 threads: thread = (batch b = t/64, bucket bk = t%64).
__global__ __launch_bounds__(256) void k2_scan(
    const int* __restrict__ hist, int* __restrict__ chunkOffset)
{
    const int t = threadIdx.x;
    const int b = t >> 6;
    const int bk = t & 63;
    const int lane = t & 63;

    int total = 0;
    for (int c = 0; c < NC32; ++c)
        total += hist[((size_t)b * NC32 + c) * NBK + bk];

    int incl = total;
#pragma unroll
    for (int off = 1; off < 64; off <<= 1) {
        int n = __shfl_up(incl, off, 64);
        if (lane >= off) incl += n;
    }
    int run = incl - total;   // exclusive prefix over buckets = bucketStart

    for (int c = 0; c < NC32; ++c) {
        int h = hist[((size_t)b * NC32 + c) * NBK + bk];
        chunkOffset[((size_t)b * NC32 + c) * NBK + bk] = run;
        run += h;
    }
}

// Stable scatter: 32-token chunks; rank via ballot restricted to own 32-lane half.
__global__ __launch_bounds__(256) void k3_scatter(
    const int* __restrict__ buckets, const int* __restrict__ chunkOffset,
    int* __restrict__ out)
{
    const int gid = blockIdx.x * 256 + threadIdx.x;  // 0..16383
    const int b = gid >> 12;
    const int s = gid & (S_LEN - 1);
    const int chunk = s >> 5;                        // 32-token chunk
    const int lane = threadIdx.x & 63;

    const int bk = buckets[gid];

    unsigned long long m = ~0ull;
#pragma unroll
    for (int i = 0; i < 6; ++i) {
        unsigned long long bi = __ballot((bk >> i) & 1);
        m &= ((bk >> i) & 1) ? bi : ~bi;
    }
    const unsigned int m32 = (unsigned int)(m >> (lane & 32));
    const int rank = __popc(m32 & ((1u << (lane & 31)) - 1u));

    const int pos = chunkOffset[((size_t)b * NC32 + chunk) * NBK + bk] + rank;
    out[(size_t)b * S_LEN + pos] = s;
}

extern "C" void kernel_launch(void* const* d_in, const int* in_sizes, int n_in,
                              void* d_out, int out_size, void* d_ws, size_t ws_size,
                              hipStream_t stream) {
    const float* Q = (const float*)d_in[0];
    // d_in[1] = key, d_in[2] = value: dead code in the reference, never read.
    const float* R = (const float*)d_in[3];

    int* buckets     = (int*)d_ws;                      // 16384 ints
    int* hist        = buckets + B_DIM * S_LEN;         // 4*128*64 = 32768 ints
    int* chunkOffset = hist + B_DIM * NC32 * NBK;       // 32768 ints

    k1_buckets<<<B_DIM * NC32, 256, 0, stream>>>(Q, R, buckets, hist);
    k2_scan   <<<1,            256, 0, stream>>>(hist, chunkOffset);
    k3_scatter<<<(B_DIM * S_LEN) / 256, 256, 0, stream>>>(buckets, chunkOffset, (int*)d_out);
}

// Round 10
// 42.724 us; speedup vs baseline: 3.6689x; 3.6689x over previous
//
#include <hip/hip_runtime.h>

// LSHAttention: reference returns ONLY sticker = argsort(buckets) [B,S] int32.
// B=4, S=4096, D=1024, NR=32, 64 buckets.
//
// k1: grid 512 = (b:4, c32:128), 512 thr = 8 waves, full K, 2 blocks/CU.
//   Thread = (tok_t:4, r_t:4, kl:4); wave w; k-quad kq = w*4+kl per tile.
//   acc = 8 tok x 8 r = 64 f32 (+rv 32 + qv 4 => ~115 VGPR, under the
//   empirical 128 ceiling that spilled R2/R8/R9).
//   K-tiles of 128, double-buffered, staged via global_load_lds width=16
//   (no staging regs, no ds_write): linear LDS dest + PRE-SWIZZLED global
//   source; swizzled ds_read on consume (T21 both-sides pattern).
//     Q layout: slot = tok*32 + (kq ^ (tok&7) ^ (((tok>>3)&1)<<2))   [f4]
//       read groups: kl (bits0-1) + (w^tok_t)&1 (bit2) -> 8 grp x 2-way.
//     R layout: slot = k*8 + (rq ^ ((k>>2)&3))                        [f4]
//       read groups: (r_t*2+p) ^ kl -> 8 grp x 2-way.  Both free (m136).
//   Counted vmcnt(4): tile tau+1's 4 loads stay in flight across compute.
//   Epilogue: shfl_xor(1,2) kl-reduce, 8-slice LDS dump+sum, argmax, hist.
// k2: offset scan (128 chunks); k3: stable scatter (verified rounds 7-9).

#define B_DIM 4
#define S_LEN 4096
#define D_DIM 1024
#define NRR 32
#define NBK 64
#define TMK 32                  // tokens per block = hist chunk
#define NC32 (S_LEN / TMK)      // 128 chunks
#define NT 8                    // 8 K-tiles of 128

typedef const __attribute__((address_space(1))) void* gas_t;
typedef __attribute__((address_space(3))) void* las_t;

__global__ __launch_bounds__(512, 4)
void k1_buckets(const float* __restrict__ Q, const float* __restrict__ R,
                int* __restrict__ buckets, int* __restrict__ hist)
{
    __shared__ float4 smem4[4096];     // Qb0 Qb1 Rb0 Rb1 (16 KB each)
    __shared__ float xs[TMK * 33];
    __shared__ int cnt[NBK];

    const int t = threadIdx.x;
    const int b = blockIdx.x >> 7;
    const int c32 = blockIdx.x & 127;

    const int w = t >> 6;
    const int lane = t & 63;
    const int tok_t = lane >> 4;        // 4 groups x 8 tokens
    const int r_t = (lane >> 2) & 3;    // 4 groups x 8 r
    const int kl = lane & 3;            // 4-way k split in wave
    const int kq = w * 4 + kl;          // k-quad within tile [0,32)
    const int qx = kq ^ ((tok_t & 1) << 2);

    const float4* Qg4 = (const float4*)(Q + ((size_t)b * S_LEN + c32 * TMK) * D_DIM);
    const float4* Rg4 = (const float4*)(R + (size_t)b * D_DIM * NRR);

    // pre-swizzled gload sources: lane-linear LDS dest = swizzled layout
    const float4* qsrc[2];
    const float4* rsrc[2];
#pragma unroll
    for (int i = 0; i < 2; ++i) {
        const int f = i * 512 + t;
        const int tok = f >> 5, s = f & 31;
        const int swz = (tok & 7) ^ (((tok >> 3) & 1) << 2);
        qsrc[i] = Qg4 + (size_t)tok * 256 + (s ^ swz);
        const int kloc = f >> 3, rq = f & 7;
        rsrc[i] = Rg4 + (size_t)kloc * 8 + (rq ^ ((kloc >> 2) & 3));
    }
    const int dwb = t & ~63;            // wave-uniform dest base (f4 units)

#define ISSUE(TILE, D)                                                        \
    {                                                                         \
        _Pragma("unroll")                                                     \
        for (int i = 0; i < 2; ++i) {                                         \
            __builtin_amdgcn_global_load_lds(                                 \
                (gas_t)(qsrc[i] + (TILE) * 32),                               \
                (las_t)&smem4[(D) * 1024 + i * 512 + dwb], 16, 0, 0);         \
            __builtin_amdgcn_global_load_lds(                                 \
                (gas_t)(rsrc[i] + (size_t)(TILE) * 1024),                     \
                (las_t)&smem4[2048 + (D) * 1024 + i * 512 + dwb], 16, 0, 0);  \
        }                                                                     \
    }

#define COMPUTE(D)                                                            \
    {                                                                         \
        const float4* qb = smem4 + (D) * 1024;                                \
        const float4* rb = smem4 + 2048 + (D) * 1024;                         \
        float4 rv[4][2];                                                      \
        _Pragma("unroll")                                                     \
        for (int kk = 0; kk < 4; ++kk)                                        \
            _Pragma("unroll")                                                 \
            for (int p = 0; p < 2; ++p)                                       \
                rv[kk][p] = rb[kq * 32 + kk * 8 + ((r_t * 2 + p) ^ kl)];      \
        _Pragma("unroll")                                                     \
        for (int j = 0; j < 8; ++j) {                                         \
            const float4 qv = qb[tok_t * 256 + j * 32 + (qx ^ j)];            \
            _Pragma("unroll")                                                 \
            for (int kk = 0; kk < 4; ++kk) {                                  \
                const float s = kk == 0 ? qv.x : kk == 1 ? qv.y               \
                              : kk == 2 ? qv.z : qv.w;                        \
                _Pragma("unroll")                                             \
                for (int p = 0; p < 2; ++p) {                                 \
                    acc[j][p].x = fmaf(s, rv[kk][p].x, acc[j][p].x);          \
                    acc[j][p].y = fmaf(s, rv[kk][p].y, acc[j][p].y);          \
                    acc[j][p].z = fmaf(s, rv[kk][p].z, acc[j][p].z);          \
                    acc[j][p].w = fmaf(s, rv[kk][p].w, acc[j][p].w);          \
                }                                                             \
            }                                                                 \
        }                                                                     \
    }

    float4 acc[8][2];
#pragma unroll
    for (int j = 0; j < 8; ++j) {
        acc[j][0] = make_float4(0.f, 0.f, 0.f, 0.f);
        acc[j][1] = make_float4(0.f, 0.f, 0.f, 0.f);
    }

    ISSUE(0, 0)
    for (int tau = 0; tau < NT; ++tau) {
        if (tau + 1 < NT) {
            ISSUE(tau + 1, (tau + 1) & 1)
            asm volatile("s_waitcnt vmcnt(4)" ::: "memory");   // tau's 4 landed
        } else {
            asm volatile("s_waitcnt vmcnt(0)" ::: "memory");
        }
        __syncthreads();
        COMPUTE(tau & 1)
        __syncthreads();
    }
#undef ISSUE
#undef COMPUTE

    // ---- reduce over kl (lane bits 0-1): lanes kl=0 hold wave partial ----
#pragma unroll
    for (int j = 0; j < 8; ++j)
#pragma unroll
        for (int p = 0; p < 2; ++p) {
            acc[j][p].x += __shfl_xor(acc[j][p].x, 1, 64);
            acc[j][p].y += __shfl_xor(acc[j][p].y, 1, 64);
            acc[j][p].z += __shfl_xor(acc[j][p].z, 1, 64);
            acc[j][p].w += __shfl_xor(acc[j][p].w, 1, 64);
            acc[j][p].x += __shfl_xor(acc[j][p].x, 2, 64);
            acc[j][p].y += __shfl_xor(acc[j][p].y, 2, 64);
            acc[j][p].z += __shfl_xor(acc[j][p].z, 2, 64);
            acc[j][p].w += __shfl_xor(acc[j][p].w, 2, 64);
        }

    if (t < NBK) cnt[t] = 0;
    // ---- dump 8 wave-slices [32 tok][8 rq f4] into smem4[0..2048) ----
    if (kl == 0) {
#pragma unroll
        for (int j = 0; j < 8; ++j) {
            const int tok = tok_t * 8 + j;
            smem4[w * 256 + tok * 8 + r_t * 2 + 0] = acc[j][0];
            smem4[w * 256 + tok * 8 + r_t * 2 + 1] = acc[j][1];
        }
    }
    __syncthreads();

    // ---- sum 8 slices (256 f4 positions over first 256 threads) ----
    if (t < 256) {
        float4 s = smem4[t];
#pragma unroll
        for (int ww = 1; ww < 8; ++ww) {
            const float4 v = smem4[ww * 256 + t];
            s.x += v.x; s.y += v.y; s.z += v.z; s.w += v.w;
        }
        const int tok = t >> 3, r2 = t & 7;
        xs[tok * 33 + r2 * 4 + 0] = s.x;
        xs[tok * 33 + r2 * 4 + 1] = s.y;
        xs[tok * 33 + r2 * 4 + 2] = s.z;
        xs[tok * 33 + r2 * 4 + 3] = s.w;
    }
    __syncthreads();

    if (t < TMK) {
        // argmax(concat[xR,-xR]) with first-occurrence tie-break
        float m1 = xs[t * 33 + 0]; int i1 = 0;
        float m2 = m1;             int i2 = 0;
#pragma unroll
        for (int r = 1; r < NRR; ++r) {
            const float v = xs[t * 33 + r];
            if (v > m1) { m1 = v; i1 = r; }
            if (v < m2) { m2 = v; i2 = r; }
        }
        const int bk = (m1 >= -m2) ? i1 : (NRR + i2);
        buckets[(size_t)b * S_LEN + c32 * TMK + t] = bk;
        atomicAdd(&cnt[bk], 1);
    }
    __syncthreads();
    if (t < NBK) hist[((size_t)b * NC32 + c32) * NBK + t] = cnt[t];
}

// One block, 256 threads: thread = (batch b = t/64, bucket bk = t%64).
__global__ __launch_bounds__(256) void k2_scan(
    const int* __restrict__ hist, int* __restrict__ chunkOffset)
{
    const int t = threadIdx.x;
    const int b = t >> 6;
    const int bk = t & 63;
    const int lane = t & 63;

    int total = 0;
    for (int c = 0; c < NC32; ++c)
        total += hist[((size_t)b * NC32 + c) * NBK + bk];

    int incl = total;
#pragma unroll
    for (int off = 1; off < 64; off <<= 1) {
        int n = __shfl_up(incl, off, 64);
        if (lane >= off) incl += n;
    }
    int run = incl - total;   // exclusive prefix over buckets = bucketStart

    for (int c = 0; c < NC32; ++c) {
        int h = hist[((size_t)b * NC32 + c) * NBK + bk];
        chunkOffset[((size_t)b * NC32 + c) * NBK + bk] = run;
        run += h;
    }
}

// Stable scatter: 32-token chunks; rank via ballot restricted to own 32-lane half.
__global__ __launch_bounds__(256) void k3_scatter(
    const int* __restrict__ buckets, const int* __restrict__ chunkOffset,
    int* __restrict__ out)
{
    const int gid = blockIdx.x * 256 + threadIdx.x;  // 0..16383
    const int b = gid >> 12;
    const int s = gid & (S_LEN - 1);
    const int chunk = s >> 5;                        // 32-token chunk
    const int lane = threadIdx.x & 63;

    const int bk = buckets[gid];

    unsigned long long m = ~0ull;
#pragma unroll
    for (int i = 0; i < 6; ++i) {
        unsigned long long bi = __ballot((bk >> i) & 1);
        m &= ((bk >> i) & 1) ? bi : ~bi;
    }
    const unsigned int m32 = (unsigned int)(m >> (lane & 32));
    const int rank = __popc(m32 & ((1u << (lane & 31)) - 1u));

    const int pos = chunkOffset[((size_t)b * NC32 + chunk) * NBK + bk] + rank;
    out[(size_t)b * S_LEN + pos] = s;
}

extern "C" void kernel_launch(void* const* d_in, const int* in_sizes, int n_in,
                              void* d_out, int out_size, void* d_ws, size_t ws_size,
                              hipStream_t stream) {
    const float* Q = (const float*)d_in[0];
    // d_in[1] = key, d_in[2] = value: dead code in the reference, never read.
    const float* R = (const float*)d_in[3];

    int* buckets     = (int*)d_ws;                      // 16384 ints
    int* hist        = buckets + B_DIM * S_LEN;         // 4*128*64 = 32768 ints
    int* chunkOffset = hist + B_DIM * NC32 * NBK;       // 32768 ints

    k1_buckets<<<B_DIM * NC32, 512, 0, stream>>>(Q, R, buckets, hist);
    k2_scan   <<<1,            256, 0, stream>>>(hist, chunkOffset);
    k3_scatter<<<(B_DIM * S_LEN) / 256, 256, 0, stream>>>(buckets, chunkOffset, (int*)d_out);
}